// Round 7
// baseline (466.711 us; speedup 1.0000x reference)
//
#include <hip/hip_runtime.h>

#define BATCH 4096
#define T 256
#define IN 64
#define CELL 128
#define ZDIM 256
#define OUTD 64
#define TILE 16    // MFMA tile rows
#define MREAL 8    // real batch rows per block (rows 8-15 duplicate 0-7)

using f32x4 = __attribute__((ext_vector_type(4))) float;
using f4    = __attribute__((ext_vector_type(4))) float;
using h16x8 = __attribute__((ext_vector_type(8))) _Float16;
using fp16x2 = __attribute__((ext_vector_type(2))) __fp16;   // cvt_pkrtz result type
typedef unsigned int u32t;

union h8cast { h16x8 v; fp16x2 h[4]; };

// One recurrence step. Reads c(fp16) from cbuf[P], writes c'(fp16) to cbuf[P^1].
// XC* hold x(TT) raw fp32 (loaded 2 steps ago); after converting, the same
// registers are refilled with x(TT+2) — 2-step-deep global prefetch, never
// drained by a barrier (raw s_barrier + lgkmcnt(0) only).
#define STEP(XC0, XC1, XC2, XC3, TT, P)                                         \
  {                                                                             \
    /* c-fragment LDS reads first: latency hides under the converts */          \
    const char* cb_ = cbuf[P];                                                  \
    h16x8 ca0 = *(const h16x8*)(cb_ + ro[0]);                                   \
    h16x8 ca1 = *(const h16x8*)(cb_ + ro[1]);                                   \
    h16x8 ca2 = *(const h16x8*)(cb_ + ro[2]);                                   \
    h16x8 ca3 = *(const h16x8*)(cb_ + ro[3]);                                   \
    /* convert x(TT) to fp16 A-frags (compiler emits counted vmcnt here) */     \
    h8cast ux0, ux1;                                                            \
    ux0.h[0] = __builtin_amdgcn_cvt_pkrtz(XC0[0], XC0[1]);                      \
    ux0.h[1] = __builtin_amdgcn_cvt_pkrtz(XC0[2], XC0[3]);                      \
    ux0.h[2] = __builtin_amdgcn_cvt_pkrtz(XC1[0], XC1[1]);                      \
    ux0.h[3] = __builtin_amdgcn_cvt_pkrtz(XC1[2], XC1[3]);                      \
    ux1.h[0] = __builtin_amdgcn_cvt_pkrtz(XC2[0], XC2[1]);                      \
    ux1.h[1] = __builtin_amdgcn_cvt_pkrtz(XC2[2], XC2[3]);                      \
    ux1.h[2] = __builtin_amdgcn_cvt_pkrtz(XC3[0], XC3[1]);                      \
    ux1.h[3] = __builtin_amdgcn_cvt_pkrtz(XC3[2], XC3[3]);                      \
    const h16x8 xa0 = ux0.v, xa1 = ux1.v;                                       \
    /* refill freed registers with x(TT+2): 2-step prefetch depth */            \
    {                                                                           \
      const int tn = (TT) + 2 < T ? (TT) + 2 : T - 1;                           \
      const float* xp = xrow + (size_t)tn * IN;                                 \
      XC0 = *(const f4*)(xp + 8 * g);                                           \
      XC1 = *(const f4*)(xp + 8 * g + 4);                                       \
      XC2 = *(const f4*)(xp + 32 + 8 * g);                                      \
      XC3 = *(const f4*)(xp + 32 + 8 * g + 4);                                  \
    }                                                                           \
    /* two parallel depth-3 MFMA chains per gate */                             \
    f32x4 accfa = {biasf, biasf, biasf, biasf};                                 \
    f32x4 accga = {biasg, biasg, biasg, biasg};                                 \
    f32x4 accfb = {0.f, 0.f, 0.f, 0.f};                                         \
    f32x4 accgb = {0.f, 0.f, 0.f, 0.f};                                         \
    accfa = __builtin_amdgcn_mfma_f32_16x16x32_f16(xa0, bf0, accfa, 0, 0, 0);   \
    accga = __builtin_amdgcn_mfma_f32_16x16x32_f16(xa0, bg0, accga, 0, 0, 0);   \
    accfb = __builtin_amdgcn_mfma_f32_16x16x32_f16(xa1, bf1, accfb, 0, 0, 0);   \
    accgb = __builtin_amdgcn_mfma_f32_16x16x32_f16(xa1, bg1, accgb, 0, 0, 0);   \
    accfa = __builtin_amdgcn_mfma_f32_16x16x32_f16(ca0, bf2, accfa, 0, 0, 0);   \
    accga = __builtin_amdgcn_mfma_f32_16x16x32_f16(ca0, bg2, accga, 0, 0, 0);   \
    accfb = __builtin_amdgcn_mfma_f32_16x16x32_f16(ca1, bf3, accfb, 0, 0, 0);   \
    accgb = __builtin_amdgcn_mfma_f32_16x16x32_f16(ca1, bg3, accgb, 0, 0, 0);   \
    accfa = __builtin_amdgcn_mfma_f32_16x16x32_f16(ca2, bf4, accfa, 0, 0, 0);   \
    accga = __builtin_amdgcn_mfma_f32_16x16x32_f16(ca2, bg4, accga, 0, 0, 0);   \
    accfb = __builtin_amdgcn_mfma_f32_16x16x32_f16(ca3, bf5, accfb, 0, 0, 0);   \
    accgb = __builtin_amdgcn_mfma_f32_16x16x32_f16(ca3, bg5, accgb, 0, 0, 0);   \
    /* gates: f = sigmoid(zf), th = tanh(zg); inf-safe, no clamp needed */      \
    char* cn_ = cbuf[(P) ^ 1];                                                  \
    _Pragma("unroll") for (int i = 0; i < 4; ++i) {                             \
      float zf = accfa[i] + accfb[i];                                           \
      float zg = accga[i] + accgb[i];                                           \
      float fg = __builtin_amdgcn_rcpf(1.f + __expf(-zf));                      \
      float th = 1.f - 2.f * __builtin_amdgcn_rcpf(__expf(2.f * zg) + 1.f);     \
      float cn = fg * (creg[i] - th) + th;                                      \
      creg[i] = cn;                                                             \
      *(_Float16*)(cn_ + wo[i]) = (_Float16)cn;                                 \
    }                                                                           \
    /* LDS-only barrier: ds_writes visible, global prefetch stays in flight */  \
    asm volatile("s_waitcnt lgkmcnt(0)\n\ts_barrier" ::: "memory");             \
  }

__global__ __launch_bounds__(512, 2)
void llrnn_f16(const float* __restrict__ in,   // [B,T,IN]
               const float* __restrict__ Km,   // [IN,ZDIM]
               const float* __restrict__ Rm,   // [CELL,ZDIM]
               const float* __restrict__ bz,   // [ZDIM]
               const float* __restrict__ Wd,   // [CELL,OUTD]
               const float* __restrict__ bd,   // [OUTD]
               float* __restrict__ out)        // [B,OUTD]
{
  // c state as fp16 [16 rows][128 cells], chunk-XOR-swizzled, double-buffered.
  __shared__ __align__(16) char cbuf[2][TILE * CELL * 2];   // 2 x 4 KB
  __shared__ float cfin[TILE * CELL];

  const int tid = threadIdx.x;
  const int w = tid >> 6;        // wave 0..7: owns z-cols [16w,16w+16) and +128
  const int l = tid & 63;
  const int q = l & 15;          // A-row / D-col within tile
  const int g = l >> 4;          // k-group 0..3
  const int rb = blockIdx.x * MREAL;
  const int jf = 16 * w + q;     // forget-gate column
  const int jg = jf + CELL;      // cell-input column

  // zero c(t=0) buffer
  ((u32t*)cbuf[0])[tid] = 0;
  ((u32t*)cbuf[0])[tid + 512] = 0;

  // ---- preload B = [K; R] columns jf, jg as fp16 fragments ----
  h16x8 bf0, bf1, bf2, bf3, bf4, bf5, bg0, bg1, bg2, bg3, bg4, bg5;
#define LOADB(DSTF, DSTG, KT)                                                   \
  {                                                                             \
    _Pragma("unroll") for (int e = 0; e < 8; ++e) {                             \
      const int krow = 32 * (KT) + 8 * g + e;                                   \
      const float* src = ((KT) < 2) ? (Km + (size_t)krow * ZDIM)                \
                                    : (Rm + (size_t)(krow - IN) * ZDIM);        \
      DSTF[e] = (_Float16)src[jf];                                              \
      DSTG[e] = (_Float16)src[jg];                                              \
    }                                                                           \
  }
  LOADB(bf0, bg0, 0) LOADB(bf1, bg1, 1) LOADB(bf2, bg2, 2)
  LOADB(bf3, bg3, 3) LOADB(bf4, bg4, 4) LOADB(bf5, bg5, 5)
#undef LOADB
  // pin B fragments: compiler must not re-derive them from memory in the loop
  asm volatile("" : "+v"(bf0), "+v"(bf1), "+v"(bf2), "+v"(bf3), "+v"(bf4),
                    "+v"(bf5), "+v"(bg0), "+v"(bg1), "+v"(bg2), "+v"(bg3),
                    "+v"(bg4), "+v"(bg5));

  const float biasf = bz[jf];
  const float biasg = bz[jg];

  // precomputed LDS byte offsets (chunk-XOR swizzle, involution both sides)
  int ro[4];   // read: c frag kt, row q, k = 32*kt + 8g .. +8
#pragma unroll
  for (int ct = 0; ct < 4; ++ct)
    ro[ct] = q * 256 + 16 * ((4 * ct + g) ^ (q & 7));
  int wo[4];   // write: cell (row 4g+i, k = jf)
#pragma unroll
  for (int i = 0; i < 4; ++i) {
    const int r = 4 * g + i;
    wo[i] = r * 256 + 16 * ((2 * w + (q >> 3)) ^ (r & 7)) + 2 * (q & 7);
  }

  // rows 8-15 of the MFMA tile duplicate rows 0-7 (same x -> identical
  // trajectory); only rows 0-7 are real batch rows of this block.
  const float* xrow = in + (size_t)(rb + (q & 7)) * T * IN;
  // prologue: x(0) -> bufA, x(1) -> bufB
  f4 xc0 = *(const f4*)(xrow + 8 * g);
  f4 xc1 = *(const f4*)(xrow + 8 * g + 4);
  f4 xc2 = *(const f4*)(xrow + 32 + 8 * g);
  f4 xc3 = *(const f4*)(xrow + 32 + 8 * g + 4);
  f4 xn0 = *(const f4*)(xrow + IN + 8 * g);
  f4 xn1 = *(const f4*)(xrow + IN + 8 * g + 4);
  f4 xn2 = *(const f4*)(xrow + IN + 32 + 8 * g);
  f4 xn3 = *(const f4*)(xrow + IN + 32 + 8 * g + 4);

  float creg[4] = {0.f, 0.f, 0.f, 0.f};  // fp32 master state (D-layout)

  __syncthreads();   // c(t=0) zeros visible (full drain OK here, once)

  for (int t = 0; t < T; t += 2) {
    STEP(xc0, xc1, xc2, xc3, t, 0)       // even: consumes bufA, refills bufA
    STEP(xn0, xn1, xn2, xn3, t + 1, 1)   // odd:  consumes bufB, refills bufB
  }

  // ---- final c (fp32) to LDS, dense epilogue out = h @ Wd + bd ----
#pragma unroll
  for (int i = 0; i < 4; ++i)
    cfin[(4 * g + i) * CELL + jf] = creg[i];
  __syncthreads();

  const int o = tid & 63;
  const int rp = tid >> 6;  // 0..7: one real row each
  float a0 = bd[o];
#pragma unroll 4
  for (int k = 0; k < CELL; ++k)
    a0 += cfin[rp * CELL + k] * Wd[(size_t)k * OUTD + o];
  out[(size_t)(rb + rp) * OUTD + o] = a0;
}

extern "C" void kernel_launch(void* const* d_in, const int* in_sizes, int n_in,
                              void* d_out, int out_size, void* d_ws, size_t ws_size,
                              hipStream_t stream) {
  const float* in  = (const float*)d_in[0];
  const float* Km  = (const float*)d_in[1];
  const float* Rm  = (const float*)d_in[2];
  const float* bz  = (const float*)d_in[3];
  const float* Wd  = (const float*)d_in[4];
  const float* bd  = (const float*)d_in[5];
  float* out = (float*)d_out;

  dim3 grid(BATCH / MREAL);   // 512 blocks -> 2 independent blocks per CU
  dim3 block(512);            // 8 waves
  hipLaunchKernelGGL(llrnn_f16, grid, block, 0, stream,
                     in, Km, Rm, bz, Wd, bd, out);
}

// Round 8
// 171.001 us; speedup vs baseline: 2.7293x; 2.7293x over previous
//
#include <hip/hip_runtime.h>

#define BATCH 4096
#define T 256
#define IN 64
#define CELL 128
#define ZDIM 256
#define OUTD 64
#define M 16   // batch rows per block (one MFMA row-tile)

using f32x4 = __attribute__((ext_vector_type(4))) float;
using f4    = __attribute__((ext_vector_type(4))) float;
using h16x8 = __attribute__((ext_vector_type(8))) _Float16;
using fp16x2 = __attribute__((ext_vector_type(2))) __fp16;   // cvt_pkrtz result type
typedef unsigned int u32t;

union h8cast { h16x8 v; fp16x2 h[4]; };

// gate for one (f,g) accumulator pair -> 4 cells of column owned by CREG
#define GATE(FA, FB, GA, GB, CREG, WO)                                          \
    _Pragma("unroll") for (int i = 0; i < 4; ++i) {                             \
      float zf = FA[i] + FB[i];                                                 \
      float zg = GA[i] + GB[i];                                                 \
      float fg = __builtin_amdgcn_rcpf(1.f + __expf(-zf));                      \
      float th = 1.f - 2.f * __builtin_amdgcn_rcpf(__expf(2.f * zg) + 1.f);     \
      float cn = fg * (CREG[i] - th) + th;                                      \
      CREG[i] = cn;                                                             \
      *(_Float16*)(cn_ + WO[i]) = (_Float16)cn;                                 \
    }

// One recurrence step. Reads c(fp16) from cbuf[P], writes c'(fp16) to cbuf[P^1].
// XC* hold x(TT) raw fp32 (loaded 2 steps ago); refilled with x(TT+2).
#define STEP(XC0, XC1, XC2, XC3, TT, P)                                         \
  {                                                                             \
    const char* cb_ = cbuf[P];                                                  \
    h16x8 ca0 = *(const h16x8*)(cb_ + ro[0]);                                   \
    h16x8 ca1 = *(const h16x8*)(cb_ + ro[1]);                                   \
    h16x8 ca2 = *(const h16x8*)(cb_ + ro[2]);                                   \
    h16x8 ca3 = *(const h16x8*)(cb_ + ro[3]);                                   \
    h8cast ux0, ux1;                                                            \
    ux0.h[0] = __builtin_amdgcn_cvt_pkrtz(XC0[0], XC0[1]);                      \
    ux0.h[1] = __builtin_amdgcn_cvt_pkrtz(XC0[2], XC0[3]);                      \
    ux0.h[2] = __builtin_amdgcn_cvt_pkrtz(XC1[0], XC1[1]);                      \
    ux0.h[3] = __builtin_amdgcn_cvt_pkrtz(XC1[2], XC1[3]);                      \
    ux1.h[0] = __builtin_amdgcn_cvt_pkrtz(XC2[0], XC2[1]);                      \
    ux1.h[1] = __builtin_amdgcn_cvt_pkrtz(XC2[2], XC2[3]);                      \
    ux1.h[2] = __builtin_amdgcn_cvt_pkrtz(XC3[0], XC3[1]);                      \
    ux1.h[3] = __builtin_amdgcn_cvt_pkrtz(XC3[2], XC3[3]);                      \
    const h16x8 xa0 = ux0.v, xa1 = ux1.v;                                       \
    {                                                                           \
      const int tn = (TT) + 2 < T ? (TT) + 2 : T - 1;                           \
      const float* xp = xrow + (size_t)tn * IN;                                 \
      XC0 = *(const f4*)(xp + 8 * g);                                           \
      XC1 = *(const f4*)(xp + 8 * g + 4);                                       \
      XC2 = *(const f4*)(xp + 32 + 8 * g);                                      \
      XC3 = *(const f4*)(xp + 32 + 8 * g + 4);                                  \
    }                                                                           \
    /* 8 parallel depth-3 MFMA chains (4 n-tiles x 2) */                        \
    f32x4 fa0 = __builtin_amdgcn_mfma_f32_16x16x32_f16(xa0, bA0, bqA, 0, 0, 0); \
    f32x4 fb0 = __builtin_amdgcn_mfma_f32_16x16x32_f16(xa0, bB0, bqB, 0, 0, 0); \
    f32x4 ga0 = __builtin_amdgcn_mfma_f32_16x16x32_f16(xa0, bC0, bqC, 0, 0, 0); \
    f32x4 gb0 = __builtin_amdgcn_mfma_f32_16x16x32_f16(xa0, bD0, bqD, 0, 0, 0); \
    f32x4 fa1 = __builtin_amdgcn_mfma_f32_16x16x32_f16(xa1, bA1, zq, 0, 0, 0);  \
    f32x4 fb1 = __builtin_amdgcn_mfma_f32_16x16x32_f16(xa1, bB1, zq, 0, 0, 0);  \
    f32x4 ga1 = __builtin_amdgcn_mfma_f32_16x16x32_f16(xa1, bC1, zq, 0, 0, 0);  \
    f32x4 gb1 = __builtin_amdgcn_mfma_f32_16x16x32_f16(xa1, bD1, zq, 0, 0, 0);  \
    fa0 = __builtin_amdgcn_mfma_f32_16x16x32_f16(ca0, bA2, fa0, 0, 0, 0);       \
    fb0 = __builtin_amdgcn_mfma_f32_16x16x32_f16(ca0, bB2, fb0, 0, 0, 0);       \
    ga0 = __builtin_amdgcn_mfma_f32_16x16x32_f16(ca0, bC2, ga0, 0, 0, 0);       \
    gb0 = __builtin_amdgcn_mfma_f32_16x16x32_f16(ca0, bD2, gb0, 0, 0, 0);       \
    fa1 = __builtin_amdgcn_mfma_f32_16x16x32_f16(ca1, bA3, fa1, 0, 0, 0);       \
    fb1 = __builtin_amdgcn_mfma_f32_16x16x32_f16(ca1, bB3, fb1, 0, 0, 0);       \
    ga1 = __builtin_amdgcn_mfma_f32_16x16x32_f16(ca1, bC3, ga1, 0, 0, 0);       \
    gb1 = __builtin_amdgcn_mfma_f32_16x16x32_f16(ca1, bD3, gb1, 0, 0, 0);       \
    fa0 = __builtin_amdgcn_mfma_f32_16x16x32_f16(ca2, bA4, fa0, 0, 0, 0);       \
    fb0 = __builtin_amdgcn_mfma_f32_16x16x32_f16(ca2, bB4, fb0, 0, 0, 0);       \
    ga0 = __builtin_amdgcn_mfma_f32_16x16x32_f16(ca2, bC4, ga0, 0, 0, 0);       \
    gb0 = __builtin_amdgcn_mfma_f32_16x16x32_f16(ca2, bD4, gb0, 0, 0, 0);       \
    fa1 = __builtin_amdgcn_mfma_f32_16x16x32_f16(ca3, bA5, fa1, 0, 0, 0);       \
    fb1 = __builtin_amdgcn_mfma_f32_16x16x32_f16(ca3, bB5, fb1, 0, 0, 0);       \
    ga1 = __builtin_amdgcn_mfma_f32_16x16x32_f16(ca3, bC5, ga1, 0, 0, 0);       \
    gb1 = __builtin_amdgcn_mfma_f32_16x16x32_f16(ca3, bD5, gb1, 0, 0, 0);       \
    char* cn_ = cbuf[(P) ^ 1];                                                  \
    GATE(fa0, fa1, ga0, ga1, cregA, woA)                                        \
    GATE(fb0, fb1, gb0, gb1, cregB, woB)                                        \
    /* LDS-only barrier: ds_writes visible, global prefetch stays in flight */  \
    asm volatile("s_waitcnt lgkmcnt(0)\n\ts_barrier" ::: "memory");             \
  }

__global__ __launch_bounds__(256, 1)
void llrnn_f16(const float* __restrict__ in,   // [B,T,IN]
               const float* __restrict__ Km,   // [IN,ZDIM]
               const float* __restrict__ Rm,   // [CELL,ZDIM]
               const float* __restrict__ bz,   // [ZDIM]
               const float* __restrict__ Wd,   // [CELL,OUTD]
               const float* __restrict__ bd,   // [OUTD]
               float* __restrict__ out)        // [B,OUTD]
{
  // c state as fp16 [16 rows][128 cells], chunk-XOR-swizzled, double-buffered.
  __shared__ __align__(16) char cbuf[2][M * CELL * 2];   // 2 x 4 KB
  __shared__ float cfin[M * CELL];

  const int tid = threadIdx.x;
  const int w = tid >> 6;        // wave 0..3: owns z-cols [32w,32w+32) and +128
  const int l = tid & 63;
  const int q = l & 15;          // A-row / D-col within tile
  const int g = l >> 4;          // k-group 0..3
  const int rb = blockIdx.x * M;
  const int jA = 32 * w + q;          // f column, n-tile 0
  const int jB = 32 * w + 16 + q;     // f column, n-tile 1

  // zero c(t=0) buffer (4 KB, 256 threads x 4 u32)
  {
    u32t* z0 = (u32t*)cbuf[0];
    z0[tid] = 0; z0[tid + 256] = 0; z0[tid + 512] = 0; z0[tid + 768] = 0;
  }

  // ---- preload weight columns jA, jB (f) and +128 (g) as fp16 frags ----
  h16x8 bA0,bA1,bA2,bA3,bA4,bA5, bB0,bB1,bB2,bB3,bB4,bB5,
        bC0,bC1,bC2,bC3,bC4,bC5, bD0,bD1,bD2,bD3,bD4,bD5;
#define LOADW(DST, COL, KT)                                                     \
  {                                                                             \
    _Pragma("unroll") for (int e = 0; e < 8; ++e) {                             \
      const int krow = 32 * (KT) + 8 * g + e;                                   \
      const float* src = ((KT) < 2) ? (Km + (size_t)krow * ZDIM)                \
                                    : (Rm + (size_t)(krow - IN) * ZDIM);        \
      DST[e] = (_Float16)src[COL];                                              \
    }                                                                           \
  }
  LOADW(bA0,jA,0) LOADW(bA1,jA,1) LOADW(bA2,jA,2) LOADW(bA3,jA,3) LOADW(bA4,jA,4) LOADW(bA5,jA,5)
  LOADW(bB0,jB,0) LOADW(bB1,jB,1) LOADW(bB2,jB,2) LOADW(bB3,jB,3) LOADW(bB4,jB,4) LOADW(bB5,jB,5)
  LOADW(bC0,jA+CELL,0) LOADW(bC1,jA+CELL,1) LOADW(bC2,jA+CELL,2) LOADW(bC3,jA+CELL,3) LOADW(bC4,jA+CELL,4) LOADW(bC5,jA+CELL,5)
  LOADW(bD0,jB+CELL,0) LOADW(bD1,jB+CELL,1) LOADW(bD2,jB+CELL,2) LOADW(bD3,jB+CELL,3) LOADW(bD4,jB+CELL,4) LOADW(bD5,jB+CELL,5)
#undef LOADW
  f32x4 zq = {0.f, 0.f, 0.f, 0.f};
  // pin weight frags + zero quad so they are never re-derived in the loop
  asm volatile("" : "+v"(bA0),"+v"(bA1),"+v"(bA2),"+v"(bA3),"+v"(bA4),"+v"(bA5),
                    "+v"(bB0),"+v"(bB1),"+v"(bB2),"+v"(bB3),"+v"(bB4),"+v"(bB5),
                    "+v"(bC0),"+v"(bC1),"+v"(bC2),"+v"(bC3),"+v"(bC4),"+v"(bC5),
                    "+v"(bD0),"+v"(bD1),"+v"(bD2),"+v"(bD3),"+v"(bD4),"+v"(bD5),
                    "+v"(zq));

  const float bA_ = bz[jA], bB_ = bz[jB], bC_ = bz[jA + CELL], bD_ = bz[jB + CELL];
  const f32x4 bqA = {bA_, bA_, bA_, bA_};
  const f32x4 bqB = {bB_, bB_, bB_, bB_};
  const f32x4 bqC = {bC_, bC_, bC_, bC_};
  const f32x4 bqD = {bD_, bD_, bD_, bD_};

  // LDS byte offsets (chunk-XOR swizzle; byte(r,j) = r*256 + 16*((j>>3)^(r&7)) + (2j&15))
  int ro[4];
#pragma unroll
  for (int ct = 0; ct < 4; ++ct)
    ro[ct] = q * 256 + 16 * ((4 * ct + g) ^ (q & 7));
  int woA[4], woB[4];
#pragma unroll
  for (int i = 0; i < 4; ++i) {
    const int r = 4 * g + i;
    woA[i] = r * 256 + 16 * ((4 * w + (q >> 3)) ^ (r & 7)) + ((2 * q) & 15);
    woB[i] = r * 256 + 16 * ((4 * w + 2 + (q >> 3)) ^ (r & 7)) + ((2 * q) & 15);
  }

  const float* xrow = in + (size_t)(rb + q) * T * IN;
  // prologue: x(0) -> bufA, x(1) -> bufB
  f4 xc0 = *(const f4*)(xrow + 8 * g);
  f4 xc1 = *(const f4*)(xrow + 8 * g + 4);
  f4 xc2 = *(const f4*)(xrow + 32 + 8 * g);
  f4 xc3 = *(const f4*)(xrow + 32 + 8 * g + 4);
  f4 xn0 = *(const f4*)(xrow + IN + 8 * g);
  f4 xn1 = *(const f4*)(xrow + IN + 8 * g + 4);
  f4 xn2 = *(const f4*)(xrow + IN + 32 + 8 * g);
  f4 xn3 = *(const f4*)(xrow + IN + 32 + 8 * g + 4);

  f32x4 cregA = {0.f, 0.f, 0.f, 0.f};   // fp32 master state, col jA
  f32x4 cregB = {0.f, 0.f, 0.f, 0.f};   // fp32 master state, col jB

  __syncthreads();   // c(t=0) zeros visible

  for (int t = 0; t < T; t += 2) {
    STEP(xc0, xc1, xc2, xc3, t, 0)       // even: consumes bufA, refills bufA
    STEP(xn0, xn1, xn2, xn3, t + 1, 1)   // odd:  consumes bufB, refills bufB
  }

  // ---- final c (fp32) to LDS, dense epilogue out = h @ Wd + bd ----
#pragma unroll
  for (int i = 0; i < 4; ++i) {
    cfin[(4 * g + i) * CELL + jA] = cregA[i];
    cfin[(4 * g + i) * CELL + jB] = cregB[i];
  }
  __syncthreads();

  const int o = tid & 63;
  const int rp = tid >> 6;   // 0..3: rows rp, rp+4, rp+8, rp+12
  float a0 = bd[o], a1 = bd[o], a2 = bd[o], a3 = bd[o];
#pragma unroll 4
  for (int k = 0; k < CELL; ++k) {
    const float wv = Wd[(size_t)k * OUTD + o];
    a0 += cfin[rp * CELL + k] * wv;
    a1 += cfin[(rp + 4) * CELL + k] * wv;
    a2 += cfin[(rp + 8) * CELL + k] * wv;
    a3 += cfin[(rp + 12) * CELL + k] * wv;
  }
  out[(size_t)(rb + rp) * OUTD + o] = a0;
  out[(size_t)(rb + rp + 4) * OUTD + o] = a1;
  out[(size_t)(rb + rp + 8) * OUTD + o] = a2;
  out[(size_t)(rb + rp + 12) * OUTD + o] = a3;
}

extern "C" void kernel_launch(void* const* d_in, const int* in_sizes, int n_in,
                              void* d_out, int out_size, void* d_ws, size_t ws_size,
                              hipStream_t stream) {
  const float* in  = (const float*)d_in[0];
  const float* Km  = (const float*)d_in[1];
  const float* Rm  = (const float*)d_in[2];
  const float* bz  = (const float*)d_in[3];
  const float* Wd  = (const float*)d_in[4];
  const float* bd  = (const float*)d_in[5];
  float* out = (float*)d_out;

  dim3 grid(BATCH / M);   // 256 blocks -> 1 per CU
  dim3 block(256);        // 4 waves -> 1 per SIMD
  hipLaunchKernelGGL(llrnn_f16, grid, block, 0, stream,
                     in, Km, Rm, bz, Wd, bd, out);
}